// Round 6
// baseline (324.233 us; speedup 1.0000x reference)
//
#include <hip/hip_runtime.h>
#include <hip/hip_bf16.h>

// GRU policy: B=2048, T=512, V=4, E=64, H=128.
// R19 = R16-structure (254us best) + LDS-PIPE OFFLOAD:
//  - gi table (10 floats x 4 tokens = 40 VGPR) lives in REGISTERS; per-step
//    select = 30 v_cndmask (static indexing). Deletes 3 LDS reads/wave/step.
//  - tokens transposed xs2[r][t]; ONE ds_read_b64 per 8 steps per lane,
//    bytes extracted at compile-time offsets (8-step unrolled octet loop).
//  - split-K REVERTED (R18: +17us, add sits on a1->exp2 gate chain).
//  - read-side replication kept (cols 8-15 read hbuf[m&7], broadcast free;
//    single b32 write; 8-row hbuf).
// Model: LDS pipe is CU-SHARED and was the largest step term (72 ops x ~8cy
// ~ 580cy of 1190cy step). R19: 72 -> 41 ops/CU/step (~330cy). VALU takes
// +33 ops/wave (has slack, per-SIMD pipe).
// Ledger: overlap 0-for-7 (R4,R7,R8,R10,R11,R12,R17-2blk/CU@4.2x); R14
// bank-pad WIN; R15 DPP FAILED; R16 occupancy WIN; R18 split-K FAILED +17us,
// write-removal did NOT move conflicts (1.692e7 both) -> conflicts are reads.
// Per wave/step: 12 MFMA, 4 ds_read_b128 + 1 ds_write_b32 + b64/8steps,
// 10 trans, ~80 VALU. 1 barrier/step. 256 blocks x 512 threads.

#define B_  2048
#define T_  512
#define V_  4
#define E_  64
#define H_  128
#define G3  384
#define G3P 392            // padded LDS stride (dwords), setup-only now
#define SH  136            // h row stride (bf16 elems)
#define NB  8              // batch rows per block
#define TP  528            // xs2 row stride (bytes): 512 + 16 zero pad

#define LOG2E 1.4426950408889634f

typedef __attribute__((ext_vector_type(8))) short  short8;   // 8 bf16
typedef __attribute__((ext_vector_type(4))) float  float4v;
typedef __attribute__((ext_vector_type(2))) float  f32x2;    // -> v_pk_* f32
typedef unsigned long long ull;

__device__ __forceinline__ short bf16s(float f) {            // RNE scalar (setup only)
  union { float ff; unsigned int u; } c; c.ff = f;
  return (short)((c.u + 0x7fffu + ((c.u >> 16) & 1u)) >> 16);
}

// table[v][g] = scale_g * (b_ih[g] + sum_e W_ih[g,e]*emb[v,e] (+ b_hh[g] for g<2H))
// scale_g = -log2e for r,z rows; +2*log2e for n rows (b_hh_n NOT folded).
__global__ void gi_table_kernel(const float* __restrict__ emb,
                                const float* __restrict__ W_ih,
                                const float* __restrict__ b_ih,
                                const float* __restrict__ b_hh,
                                float* __restrict__ table) {
  int gid = blockIdx.x * blockDim.x + threadIdx.x;
  if (gid >= V_ * G3) return;
  int v = gid / G3;
  int g = gid - v * G3;
  float acc = b_ih[g];
  if (g < 2 * H_) acc += b_hh[g];
  const float* wr = W_ih + g * E_;
  const float* er = emb + v * E_;
#pragma unroll 8
  for (int e = 0; e < E_; ++e) acc += wr[e] * er[e];
  table[gid] = acc * ((g < 2 * H_) ? -LOG2E : 2.f * LOG2E);
}

#define MFMA16(A, B, C) __builtin_amdgcn_mfma_f32_16x16x32_bf16((A), (B), (C), 0, 0, 0)

__global__ __launch_bounds__(512, 2) void gru_kernel(
    const int* __restrict__ x, const float* __restrict__ W_hh,
    const float* __restrict__ b_hh, const float* __restrict__ W_fc,
    const float* __restrict__ b_fc, const float* __restrict__ table,
    float* __restrict__ out) {
  __shared__ __align__(16) short hbuf[2][NB * SH];           // bf16 h, 8 rows
  __shared__ __align__(16) unsigned char xs2[NB * TP];       // tokens [row][t], transposed
  __shared__ __align__(16) float tabS[V_ * G3P];             // gi table (setup staging)
  __shared__ __align__(16) float hf[NB * H_];                // epilogue fp32 h

  const int tid  = threadIdx.x;
  const int w    = tid >> 6;        // wave 0..7
  const int lane = tid & 63;
  const int m    = lane & 15;       // B/C col: batch (m&7), replicated in cols 8-15
  const int q    = lane >> 4;       // quad
  const int mb   = m & 7;           // batch row
  const bool isHi = (m & 8) != 0;   // false: own elems {0,1}; true: own elems {2,3}
  const int g0   = blockIdx.x * NB;

  // ---- stage x -> xs2[r][t] transposed bytes; zero the 16-byte pad ----
  for (int i = tid; i < NB * T_; i += 512) {
    int r = i >> 9;                 // 0..7
    int t = i & (T_ - 1);
    xs2[r * TP + t] = (unsigned char)(x[(g0 + r) * T_ + t] & 3);
  }
  if (tid < NB * 16) {
    int r = tid >> 4, k = tid & 15;
    xs2[r * TP + T_ + k] = 0;
  }
  // ---- stage gi table to LDS (setup only; read into registers below) ----
  for (int v = 0; v < V_; ++v)
    for (int g = tid; g < G3; g += 512) tabS[v * G3P + g] = table[v * G3 + g];
  // ---- zero both h buffers (h0 = 0) ----
  for (int i = tid; i < 2 * NB * SH; i += 512) hbuf[0][i] = 0;

  // ---- persistent A-fragments: W_hh tiles (pre-scaled), A[g=m][k=q*8+j] ----
  short8 wA[3][4];
#pragma unroll
  for (int s = 0; s < 3; ++s) {
    const float sc = (s < 2) ? -LOG2E : 2.f * LOG2E;
    const float* wrow = W_hh + (s * H_ + w * 16 + m) * H_;
#pragma unroll
    for (int ks = 0; ks < 4; ++ks) {
      const float* p = wrow + ks * 32 + q * 8;
      short8 f;
#pragma unroll
      for (int jj = 0; jj < 8; ++jj) f[jj] = bf16s(p[jj] * sc);
      wA[s][ks] = f;
    }
  }

  const int c0  = w * 16 + q * 4;          // C-row base (hdim) of this lane's accum
  const int c0r = c0 + (isHi ? 2 : 0);     // this lane's 2 assigned hdims
  float4v bhnC;                            // a2 chain C-init: b_hh_n * 2log2e
  {
    const float* p = b_hh + 2 * H_ + c0;
#pragma unroll
    for (int i = 0; i < 4; ++i) bhnC[i] = p[i] * 2.f * LOG2E;
  }
  f32x2 hA = {0.f, 0.f};            // this lane's 2 h values (hdim c0r+{0,1}, batch mb)

  __syncthreads();

  // ---- gi table slices -> REGISTERS (40 VGPR; compile-time indices only) ----
  float4v gRv[4], gZv[4];
  f32x2   gNv[4];
#pragma unroll
  for (int v = 0; v < 4; ++v) {
    const float* tb = &tabS[v * G3P + c0];
    gRv[v] = *(const float4v*)(tb);
    gZv[v] = *(const float4v*)(tb + H_);
    gNv[v] = *(const f32x2*)(tb + 2 * H_ + (isHi ? 2 : 0));
  }

  // ---- token byte stream: 8 tokens per ds_read_b64 ----
  ull cur8 = *(const ull*)&xs2[mb * TP];   // tokens [0..8)

  // 2-bit token select over 4 register variants (cndmask chains, no indexing)
  auto pickf = [&](unsigned tk, float a, float b, float c, float d) -> float {
    float lo = (tk & 1u) ? b : a;
    float hi = (tk & 1u) ? d : c;
    return (tk & 2u) ? hi : lo;
  };
  auto pick4 = [&](unsigned tk, const float4v& a, const float4v& b,
                   const float4v& c, const float4v& d) -> float4v {
    float4v r;
#pragma unroll
    for (int i = 0; i < 4; ++i) r[i] = pickf(tk, a[i], b[i], c[i], d[i]);
    return r;
  };

  // ---- prologue: gi(token[0]) into set A ----
  float4v gAR, gAZ, gBR, gBZ;
  f32x2 gAN, gBN;
  {
    unsigned tk = (unsigned)(cur8 & 3ull);
    gAR = pick4(tk, gRv[0], gRv[1], gRv[2], gRv[3]);
    gAZ = pick4(tk, gZv[0], gZv[1], gZv[2], gZv[3]);
    gAN.x = pickf(tk, gNv[0].x, gNv[1].x, gNv[2].x, gNv[3].x);
    gAN.y = pickf(tk, gNv[0].y, gNv[1].y, gNv[2].y, gNv[3].y);
  }

  const f32x2 one2 = {1.f, 1.f};

  // own-element select: lanes m<8 take elems {0,1}, lanes m>=8 take {2,3}.
  auto sel = [&](const float4v& xv) -> f32x2 {
    f32x2 r;
    r.x = isHi ? xv[2] : xv[0];
    r.y = isHi ? xv[3] : xv[1];
    return r;
  };

  auto step = [&](int FROM, int TO, unsigned tk,
                  float4v& guR, float4v& guZ, f32x2& guN,       // gi used this step
                  float4v& glR, float4v& glZ, f32x2& glN) {     // gi selected for next
    // h fragments — the ONLY LDS reads in the loop; read-side replication
    const short* rbp = &hbuf[FROM][mb * SH + q * 8];
    short8 h0 = *(const short8*)(rbp);
    short8 h1 = *(const short8*)(rbp + 32);
    short8 h2 = *(const short8*)(rbp + 64);
    short8 h3 = *(const short8*)(rbp + 96);

    // ---- all 12 MFMAs up front; a0 (r) leads, a2, a1 (z) last ----
    float4v a0 = MFMA16(wA[0][0], h0, guR);
    a0 = MFMA16(wA[0][1], h1, a0);
    a0 = MFMA16(wA[0][2], h2, a0);
    a0 = MFMA16(wA[0][3], h3, a0);
    float4v a2 = MFMA16(wA[2][0], h0, bhnC);
    a2 = MFMA16(wA[2][1], h1, a2);
    a2 = MFMA16(wA[2][2], h2, a2);
    a2 = MFMA16(wA[2][3], h3, a2);
    float4v a1 = MFMA16(wA[1][0], h0, guZ);
    a1 = MFMA16(wA[1][1], h1, a1);
    a1 = MFMA16(wA[1][2], h2, a1);
    a1 = MFMA16(wA[1][3], h3, a1);

    // ---- own 2 elems; r = rcp(1+Er) scalar trans under the queue drain ----
    f32x2 a0e = sel(a0);
    f32x2 rr;
    rr.x = __builtin_amdgcn_rcpf(1.f + __builtin_amdgcn_exp2f(a0e.x));
    rr.y = __builtin_amdgcn_rcpf(1.f + __builtin_amdgcn_exp2f(a0e.y));
    f32x2 a2e = sel(a2);
    f32x2 a1e = sel(a1);

    // ---- next-step gi: register cndmask select (no LDS) ----
    glR = pick4(tk, gRv[0], gRv[1], gRv[2], gRv[3]);
    glZ = pick4(tk, gZv[0], gZv[1], gZv[2], gZv[3]);
    glN.x = pickf(tk, gNv[0].x, gNv[1].x, gNv[2].x, gNv[3].x);
    glN.y = pickf(tk, gNv[0].y, gNv[1].y, gNv[2].y, gNv[3].y);

    // ---- packed fused tail: h' = [e2n(Ez+h)+(h-Ez)] * rcp[(e2n+1)(1+Ez)] ----
    f32x2 np = rr * a2e + guN;                     // v_pk_fma_f32
    f32x2 e  = {__builtin_amdgcn_exp2f(np.x), __builtin_amdgcn_exp2f(np.y)};
    f32x2 Ez = {__builtin_amdgcn_exp2f(a1e.x), __builtin_amdgcn_exp2f(a1e.y)};
    f32x2 num = e * (Ez + hA) + (hA - Ez);         // pk_add, pk_fma, pk_add(neg)
    f32x2 den = (e + one2) * (one2 + Ez);          // pk_add x2, pk_mul
    f32x2 rc  = {__builtin_amdgcn_rcpf(den.x), __builtin_amdgcn_rcpf(den.y)};
    hA = num * rc;                                 // pk_mul
    unsigned int pk0;
    asm("v_cvt_pk_bf16_f32 %0, %1, %2" : "=v"(pk0) : "v"(hA.x), "v"(hA.y));
    *(unsigned int*)(&hbuf[TO][mb * SH + c0r]) = pk0;
    __syncthreads();
  };

  // ---- octet-unrolled time loop: token extracts at compile-time offsets ----
  for (int t = 0; t < T_; t += 8) {
    ull nxt8 = *(const ull*)&xs2[mb * TP + t + 8];   // tokens [t+8..t+16); pad-safe
#pragma unroll
    for (int p = 0; p < 8; ++p) {
      // token[t+p+1] selects gi for the NEXT step
      unsigned tk = (unsigned)(((p + 1) < 8 ? (cur8 >> ((p + 1) * 8)) : nxt8) & 3ull);
      if ((p & 1) == 0) step(0, 1, tk, gAR, gAZ, gAN, gBR, gBZ, gBN);
      else              step(1, 0, tk, gBR, gBZ, gBN, gAR, gAZ, gAN);
    }
    cur8 = nxt8;
  }

  // ---- epilogue: logits = hT @ W_fc^T + b_fc ----
  hf[mb * H_ + c0r + 0] = hA.x;
  hf[mb * H_ + c0r + 1] = hA.y;
  __syncthreads();

  if (tid < NB * V_) {
    int row = tid >> 2, vo = tid & 3;
    float s = b_fc[vo];
    const float* wv = W_fc + vo * H_;
    const float* hr = &hf[row * H_];
#pragma unroll 4
    for (int k = 0; k < H_; k += 4)
      s += hr[k] * wv[k] + hr[k + 1] * wv[k + 1]
         + hr[k + 2] * wv[k + 2] + hr[k + 3] * wv[k + 3];
    out[(g0 + row) * V_ + vo] = s;
  }
}

extern "C" void kernel_launch(void* const* d_in, const int* in_sizes, int n_in,
                              void* d_out, int out_size, void* d_ws, size_t ws_size,
                              hipStream_t stream) {
  const int*   x    = (const int*)d_in[0];
  const float* emb  = (const float*)d_in[1];
  const float* W_ih = (const float*)d_in[2];
  const float* W_hh = (const float*)d_in[3];
  const float* b_ih = (const float*)d_in[4];
  const float* b_hh = (const float*)d_in[5];
  const float* W_fc = (const float*)d_in[6];
  const float* b_fc = (const float*)d_in[7];
  float* out   = (float*)d_out;
  float* table = (float*)d_ws;     // 4*384 fp32 = 6 KB

  gi_table_kernel<<<(V_ * G3 + 255) / 256, 256, 0, stream>>>(emb, W_ih, b_ih, b_hh, table);
  gru_kernel<<<B_ / NB, 512, 0, stream>>>(x, W_hh, b_hh, W_fc, b_fc, table, out);
}

// Round 7
// 272.644 us; speedup vs baseline: 1.1892x; 1.1892x over previous
//
#include <hip/hip_runtime.h>
#include <hip/hip_bf16.h>

// GRU policy: B=2048, T=512, V=4, E=64, H=128.
// R20 = verified-best reassembly: R16 structure (254us) + read-side
// replication (R18-proven conflict-neutral; mirror ds_write deleted)
// - split-K (R18: +14us) - gi-in-registers (R19: +25us; gi LDS reads are
// FREE -- removing them bought 0 time at +160cy/SIMD VALU cost).
// Model (recalibrated R19): step is SUM-behaved, 1190cy; VALU+trans ~490cy/
// SIMD is the largest term and trades ~1:1 with wall time (R13 win / R18,
// R19 losses all quantitative). trans ~8cy wave64 -> poly-exp2 loses; gi
// reads hidden -> LDS op count not binding; conflicts (1.69e7) live in
// h-reads and are time-neutral.
// Ledger: overlap 0-for-7 (R4,R7,R8,R10,R11,R12,R17-2blk/CU@4.2x); R14
// bank-pad WIN; R15 DPP FAILED; R16 occupancy WIN; R18 split-K FAILED;
// R19 gi-to-VGPR FAILED (+VALU 1:1). Structural waste left: MFMA col
// redundancy (B/CU=8 forces 8 dead cols), trans floor 5/elem.
// Per wave/step: 12 MFMA, 4 ds_read_b128(h) + 2 b128 + 1 b64 (gi) + 1 u8
// + 1 ds_write_b32, 10 trans, ~40 VALU. 1 barrier/step. 256 blocks x 512.

#define B_  2048
#define T_  512
#define V_  4
#define E_  64
#define H_  128
#define G3  384
#define G3P 392            // padded LDS stride (dwords): 392 % 32 = 8
#define SH  136            // h row stride (bf16 elems)
#define NB  8              // batch rows per block

#define LOG2E 1.4426950408889634f

typedef __attribute__((ext_vector_type(8))) short  short8;   // 8 bf16
typedef __attribute__((ext_vector_type(4))) float  float4v;
typedef __attribute__((ext_vector_type(2))) float  f32x2;    // -> v_pk_* f32

__device__ __forceinline__ short bf16s(float f) {            // RNE scalar (setup only)
  union { float ff; unsigned int u; } c; c.ff = f;
  return (short)((c.u + 0x7fffu + ((c.u >> 16) & 1u)) >> 16);
}

// table[v][g] = scale_g * (b_ih[g] + sum_e W_ih[g,e]*emb[v,e] (+ b_hh[g] for g<2H))
// scale_g = -log2e for r,z rows; +2*log2e for n rows (b_hh_n NOT folded).
__global__ void gi_table_kernel(const float* __restrict__ emb,
                                const float* __restrict__ W_ih,
                                const float* __restrict__ b_ih,
                                const float* __restrict__ b_hh,
                                float* __restrict__ table) {
  int gid = blockIdx.x * blockDim.x + threadIdx.x;
  if (gid >= V_ * G3) return;
  int v = gid / G3;
  int g = gid - v * G3;
  float acc = b_ih[g];
  if (g < 2 * H_) acc += b_hh[g];
  const float* wr = W_ih + g * E_;
  const float* er = emb + v * E_;
#pragma unroll 8
  for (int e = 0; e < E_; ++e) acc += wr[e] * er[e];
  table[gid] = acc * ((g < 2 * H_) ? -LOG2E : 2.f * LOG2E);
}

#define MFMA16(A, B, C) __builtin_amdgcn_mfma_f32_16x16x32_bf16((A), (B), (C), 0, 0, 0)

__global__ __launch_bounds__(512) void gru_kernel(
    const int* __restrict__ x, const float* __restrict__ W_hh,
    const float* __restrict__ b_hh, const float* __restrict__ W_fc,
    const float* __restrict__ b_fc, const float* __restrict__ table,
    float* __restrict__ out) {
  __shared__ __align__(16) short hbuf[2][NB * SH];           // bf16 h, 8 rows
  __shared__ __align__(16) unsigned char xs[(T_ + 2) * NB];  // tokens [t][row], 2 pad rows
  __shared__ __align__(16) float tabS[V_ * G3P];             // gi table (pre-scaled, padded)
  __shared__ __align__(16) float hf[NB * H_];                // epilogue fp32 h

  const int tid  = threadIdx.x;
  const int w    = tid >> 6;        // wave 0..7
  const int lane = tid & 63;
  const int m    = lane & 15;       // B/C col: batch (m&7), replicated in cols 8-15
  const int q    = lane >> 4;       // quad
  const int mb   = m & 7;           // batch row
  const bool isHi = (m & 8) != 0;   // false: own elems {0,1}; true: own elems {2,3}
  const int g0   = blockIdx.x * NB;

  // ---- stage x -> xs[t][r] bytes (pre-masked); zero the 2 pad rows ----
  for (int i = tid; i < NB * T_; i += 512) {
    int r = i >> 9;                 // 0..7
    int t = i & (T_ - 1);
    xs[t * NB + r] = (unsigned char)(x[(g0 + r) * T_ + t] & 3);
  }
  if (tid < 2 * NB) xs[T_ * NB + tid] = 0;
  // ---- stage gi table to LDS (padded stride: v rows land on distinct stripes) ----
  for (int v = 0; v < V_; ++v)
    for (int g = tid; g < G3; g += 512) tabS[v * G3P + g] = table[v * G3 + g];
  // ---- zero both h buffers (h0 = 0) ----
  for (int i = tid; i < 2 * NB * SH; i += 512) hbuf[0][i] = 0;

  // ---- persistent A-fragments: W_hh tiles (pre-scaled), A[g=m][k=q*8+j] ----
  short8 wA[3][4];
#pragma unroll
  for (int s = 0; s < 3; ++s) {
    const float sc = (s < 2) ? -LOG2E : 2.f * LOG2E;
    const float* wrow = W_hh + (s * H_ + w * 16 + m) * H_;
#pragma unroll
    for (int ks = 0; ks < 4; ++ks) {
      const float* p = wrow + ks * 32 + q * 8;
      short8 f;
#pragma unroll
      for (int jj = 0; jj < 8; ++jj) f[jj] = bf16s(p[jj] * sc);
      wA[s][ks] = f;
    }
  }

  const int c0  = w * 16 + q * 4;          // C-row base (hdim) of this lane's accum
  const int c0r = c0 + (isHi ? 2 : 0);     // this lane's 2 assigned hdims
  float4v bhnC;                            // a2 chain C-init: b_hh_n * 2log2e
  {
    const float* p = b_hh + 2 * H_ + c0;
#pragma unroll
    for (int i = 0; i < 4; ++i) bhnC[i] = p[i] * 2.f * LOG2E;
  }
  f32x2 hA = {0.f, 0.f};            // this lane's 2 h values (hdim c0r+{0,1}, batch mb)

  __syncthreads();

  // ---- prologue: gi(0) into set A; token byte of t=1 ----
  float4v gAR, gAZ, gBR, gBZ;
  f32x2 gAN, gBN;
  int vb;
  {
    int v0 = xs[mb];
    const float* tb = &tabS[v0 * G3P + c0];
    gAR = *(const float4v*)(tb);
    gAZ = *(const float4v*)(tb + H_);
    gAN = *(const f32x2*)(&tabS[v0 * G3P + 2 * H_ + c0r]);
    vb  = xs[NB + mb];
  }

  const f32x2 one2 = {1.f, 1.f};

  // own-element select: lanes m<8 take elems {0,1}, lanes m>=8 take {2,3}.
  auto sel = [&](const float4v& xv) -> f32x2 {
    f32x2 r;
    r.x = isHi ? xv[2] : xv[0];
    r.y = isHi ? xv[3] : xv[1];
    return r;
  };

  auto step = [&](int FROM, int TO, int t,
                  float4v& guR, float4v& guZ, f32x2& guN,       // gi used this step
                  float4v& glR, float4v& glZ, f32x2& glN) {     // gi loaded for next
    // h fragments — read-side replication: col m carries batch m&7.
    const short* rbp = &hbuf[FROM][mb * SH + q * 8];
    short8 h0 = *(const short8*)(rbp);
    short8 h1 = *(const short8*)(rbp + 32);
    short8 h2 = *(const short8*)(rbp + 64);
    short8 h3 = *(const short8*)(rbp + 96);

    // ---- next-step gi: ds_reads issued EARLY, latency hides under MFMAs ----
    int vb2 = xs[(t + 2) * NB + mb];
    const float* tbn = &tabS[vb * G3P + c0];
    glR = *(const float4v*)(tbn);
    glZ = *(const float4v*)(tbn + H_);
    glN = *(const f32x2*)(tbn + 2 * H_ + (isHi ? 2 : 0));
    vb = vb2;

    // ---- all 12 MFMAs up front; a0 (r) leads, a2, a1 (z) last ----
    float4v a0 = MFMA16(wA[0][0], h0, guR);
    a0 = MFMA16(wA[0][1], h1, a0);
    a0 = MFMA16(wA[0][2], h2, a0);
    a0 = MFMA16(wA[0][3], h3, a0);
    float4v a2 = MFMA16(wA[2][0], h0, bhnC);
    a2 = MFMA16(wA[2][1], h1, a2);
    a2 = MFMA16(wA[2][2], h2, a2);
    a2 = MFMA16(wA[2][3], h3, a2);
    float4v a1 = MFMA16(wA[1][0], h0, guZ);
    a1 = MFMA16(wA[1][1], h1, a1);
    a1 = MFMA16(wA[1][2], h2, a1);
    a1 = MFMA16(wA[1][3], h3, a1);

    // ---- own 2 elems; r = rcp(1+Er) scalar trans under the queue drain ----
    f32x2 a0e = sel(a0);
    f32x2 rr;
    rr.x = __builtin_amdgcn_rcpf(1.f + __builtin_amdgcn_exp2f(a0e.x));
    rr.y = __builtin_amdgcn_rcpf(1.f + __builtin_amdgcn_exp2f(a0e.y));
    f32x2 a2e = sel(a2);
    f32x2 a1e = sel(a1);

    // ---- packed fused tail: h' = [e2n(Ez+h)+(h-Ez)] * rcp[(e2n+1)(1+Ez)] ----
    f32x2 np = rr * a2e + guN;                     // v_pk_fma_f32
    f32x2 e  = {__builtin_amdgcn_exp2f(np.x), __builtin_amdgcn_exp2f(np.y)};
    f32x2 Ez = {__builtin_amdgcn_exp2f(a1e.x), __builtin_amdgcn_exp2f(a1e.y)};
    f32x2 num = e * (Ez + hA) + (hA - Ez);         // pk_add, pk_fma, pk_add(neg)
    f32x2 den = (e + one2) * (one2 + Ez);          // pk_add x2, pk_mul
    f32x2 rc  = {__builtin_amdgcn_rcpf(den.x), __builtin_amdgcn_rcpf(den.y)};
    hA = num * rc;                                 // pk_mul
    unsigned int pk0;
    asm("v_cvt_pk_bf16_f32 %0, %1, %2" : "=v"(pk0) : "v"(hA.x), "v"(hA.y));
    *(unsigned int*)(&hbuf[TO][mb * SH + c0r]) = pk0;
    __syncthreads();
  };

  for (int t = 0; t < T_; t += 2) {
    step(0, 1, t,     gAR, gAZ, gAN, gBR, gBZ, gBN);
    step(1, 0, t + 1, gBR, gBZ, gBN, gAR, gAZ, gAN);
  }

  // ---- epilogue: logits = hT @ W_fc^T + b_fc ----
  hf[mb * H_ + c0r + 0] = hA.x;
  hf[mb * H_ + c0r + 1] = hA.y;
  __syncthreads();

  if (tid < NB * V_) {
    int row = tid >> 2, vo = tid & 3;
    float s = b_fc[vo];
    const float* wv = W_fc + vo * H_;
    const float* hr = &hf[row * H_];
#pragma unroll 4
    for (int k = 0; k < H_; k += 4)
      s += hr[k] * wv[k] + hr[k + 1] * wv[k + 1]
         + hr[k + 2] * wv[k + 2] + hr[k + 3] * wv[k + 3];
    out[(g0 + row) * V_ + vo] = s;
  }
}

extern "C" void kernel_launch(void* const* d_in, const int* in_sizes, int n_in,
                              void* d_out, int out_size, void* d_ws, size_t ws_size,
                              hipStream_t stream) {
  const int*   x    = (const int*)d_in[0];
  const float* emb  = (const float*)d_in[1];
  const float* W_ih = (const float*)d_in[2];
  const float* W_hh = (const float*)d_in[3];
  const float* b_ih = (const float*)d_in[4];
  const float* b_hh = (const float*)d_in[5];
  const float* W_fc = (const float*)d_in[6];
  const float* b_fc = (const float*)d_in[7];
  float* out   = (float*)d_out;
  float* table = (float*)d_ws;     // 4*384 fp32 = 6 KB

  gi_table_kernel<<<(V_ * G3 + 255) / 256, 256, 0, stream>>>(emb, W_ih, b_ih, b_hh, table);
  gru_kernel<<<B_ / NB, 512, 0, stream>>>(x, W_hh, b_hh, W_fc, b_fc, table, out);
}